// Round 14
// baseline (376.228 us; speedup 1.0000x reference)
//
#include <hip/hip_runtime.h>

// rate_RNN_mante: T=1000, B=64, IN=4, H=512, OUT=3, P=2.
// Linear-split scan (r11):
//   M~_t = V_t + A0*sigma0_t + A1*sigma1_t
//   V_t  = lm*V_{t-1} + ct*Win.x_t            (input-only -> parallel pass A)
//   sigmap_t = lm*sigmap_{t-1} + s_p,{t-1}    (2-scalar serial recurrence)
//   s_p,t = pout[:,p]^T tanh(mem_t)           (wave DPP reduction)
// Pass A: 32768 independent (b,h) filters write V [B,T,H] fp32 (131 MB ws).
// Pass B: serial scan, 36 floats persistent state + 4-step register prefetch
//         of V; streams r=tanh(mem) as bf16 into the SAME slab (block-private
//         prefix overlay: r_t bytes always below the V_t read frontier).
// Pass C: parallel GEMV y = Wout . r over 64000 rows.
// Fallback (ws too small): round-7 fused kernel.

#define T_STEPS 1000
#define BATCH   64
#define H       512
#define OUTDIM  3

typedef float v2f __attribute__((ext_vector_type(2)));

#if __has_builtin(__builtin_amdgcn_exp2f)
#define EXP2(x) __builtin_amdgcn_exp2f(x)
#else
#define EXP2(x) exp2f(x)
#endif

#define LM 0.9048374180359595f                       // fp32(exp(-DT/TAUM))
#define CT (2.0f * 1.4426950408889634f * (1.0f - LM))// 2*log2e*(1-lm)

template<int CTRL, int RM>
__device__ __forceinline__ float dpp_add(float x) {
    int mv = __builtin_amdgcn_update_dpp(0, __builtin_bit_cast(int, x),
                                         CTRL, RM, 0xf, true);
    return x + __builtin_bit_cast(float, mv);
}

__device__ __forceinline__ float bcast63(float x) {
    return __builtin_bit_cast(float,
        __builtin_amdgcn_readlane(__builtin_bit_cast(int, x), 63));
}

// ---------------------------------------------------------------------------
// Pass A: V[b,t,h] = lm*V[b,t-1,h] + ct*(Win[h,:] . x[t,b,:])
// thread per (b,h); wave-uniform b -> broadcast x loads, coalesced V stores.
// ---------------------------------------------------------------------------
__global__ __launch_bounds__(256) void filter_u(
    const float* __restrict__ x,     // [T, B, 4]
    const float* __restrict__ Win,   // [H, 4]
    float* __restrict__ Vws)         // [B, T, H] fp32
{
    const int tid = blockIdx.x * 256 + threadIdx.x;
    const int b = tid >> 9;
    const int h = tid & (H - 1);
    float4 w = ((const float4*)Win)[h];
    w.x *= CT; w.y *= CT; w.z *= CT; w.w *= CT;
    const float4* xp = (const float4*)x + b;         // stride BATCH per t
    float* vp = Vws + (size_t)b * T_STEPS * H + h;
    float V = 0.0f;
#pragma unroll 4
    for (int t = 0; t < T_STEPS; ++t) {
        float4 xt = xp[(size_t)t * BATCH];
        float u = fmaf(w.x, xt.x, fmaf(w.y, xt.y, fmaf(w.z, xt.z, w.w * xt.w)));
        V = fmaf(V, LM, u);
        vp[(size_t)t * H] = V;
    }
}

// ---------------------------------------------------------------------------
// Pass B: serial scan. One wave per batch; lane owns h = 8*lane..8*lane+7.
// Persistent: A0,A1,P0,P1 (32 floats) + sigma/s (4). V prefetched 4 steps
// ahead in registers (distance ~1200cy covers HBM latency; compiler waits).
// r stored bf16 into the same slab (Rws == Vws, restrict-separated; regions
// provably disjoint at every step: r frontier t*1024+1024 <= V read t*2048).
// ---------------------------------------------------------------------------
__global__ __launch_bounds__(64, 1) void rnn_scan_sigma(
    const float* __restrict__ pin,   // [H, 2]
    const float* __restrict__ pout,  // [H, 2]
    const float* __restrict__ l,     // [2]
    const float* __restrict__ Vws,   // [B, T, H] fp32
    unsigned short* __restrict__ Rws)// bf16 overlay, same buffer
{
    const int b    = blockIdx.x;
    const int lane = threadIdx.x;
    const int hb   = 8 * lane;
    const float l0 = l[0], l1 = l[1];

    v2f A00, A01, A02, A03, A10, A11, A12, A13;
    v2f P00, P01, P02, P03, P10, P11, P12, P13;
#define WLOAD(G) do {                                                         \
    const int h0 = hb + 2 * G, h1 = h0 + 1;                                   \
    float2 pi0 = ((const float2*)pin)[h0];                                    \
    float2 pi1 = ((const float2*)pin)[h1];                                    \
    A0##G = (v2f){CT * l0 * pi0.x, CT * l0 * pi1.x};                          \
    A1##G = (v2f){CT * l1 * pi0.y, CT * l1 * pi1.y};                          \
    float2 q0 = ((const float2*)pout)[h0];                                    \
    float2 q1 = ((const float2*)pout)[h1];                                    \
    P0##G = (v2f){q0.x, q1.x};                                                \
    P1##G = (v2f){q0.y, q1.y};                                                \
} while (0)
    WLOAD(0); WLOAD(1); WLOAD(2); WLOAD(3);

    const float* vslab = Vws + (size_t)b * T_STEPS * H;
    // r slab: byte offset b*2MB == short offset b*T*H*2 (block-private)
    unsigned short* rslab = Rws + (size_t)b * T_STEPS * H * 2;

    float s0 = 0.0f, s1 = 0.0f, sg0 = 0.0f, sg1 = 0.0f;

    float4 V0a, V0b, V1a, V1b, V2a, V2b, V3a, V3b;
#define VLOAD(S, TT) do {                                                     \
    const float4* vp = (const float4*)(vslab + (size_t)(TT) * H + hb);        \
    S##a = vp[0]; S##b = vp[1];                                               \
} while (0)
    VLOAD(V0, 0); VLOAD(V1, 1); VLOAD(V2, 2); VLOAD(V3, 3);

#define PHASE(S, TT) do {                                                     \
    sg0 = fmaf(sg0, LM, s0);                                                  \
    sg1 = fmaf(sg1, LM, s1);                                                  \
    v2f va0 = {S##a.x, S##a.y}, va1 = {S##a.z, S##a.w};                       \
    v2f vb0 = {S##b.x, S##b.y}, vb1 = {S##b.z, S##b.w};                       \
    v2f m0 = va0 + A00 * sg0 + A10 * sg1;                                     \
    v2f m1 = va1 + A01 * sg0 + A11 * sg1;                                     \
    v2f m2 = vb0 + A02 * sg0 + A12 * sg1;                                     \
    v2f m3 = vb1 + A03 * sg0 + A13 * sg1;                                     \
    float e0 = EXP2(m0.x), e1 = EXP2(m0.y), e2 = EXP2(m1.x), e3 = EXP2(m1.y); \
    float e4 = EXP2(m2.x), e5 = EXP2(m2.y), e6 = EXP2(m3.x), e7 = EXP2(m3.y); \
    v2f r0 = {fmaf(-2.f, __builtin_amdgcn_rcpf(e0 + 1.f), 1.f),               \
              fmaf(-2.f, __builtin_amdgcn_rcpf(e1 + 1.f), 1.f)};              \
    v2f r1 = {fmaf(-2.f, __builtin_amdgcn_rcpf(e2 + 1.f), 1.f),               \
              fmaf(-2.f, __builtin_amdgcn_rcpf(e3 + 1.f), 1.f)};              \
    v2f r2 = {fmaf(-2.f, __builtin_amdgcn_rcpf(e4 + 1.f), 1.f),               \
              fmaf(-2.f, __builtin_amdgcn_rcpf(e5 + 1.f), 1.f)};              \
    v2f r3 = {fmaf(-2.f, __builtin_amdgcn_rcpf(e6 + 1.f), 1.f),               \
              fmaf(-2.f, __builtin_amdgcn_rcpf(e7 + 1.f), 1.f)};              \
    unsigned u0, u1, u2, u3;                                                  \
    asm("v_cvt_pk_bf16_f32 %0, %1, %2" : "=v"(u0) : "v"(r0.x), "v"(r0.y));    \
    asm("v_cvt_pk_bf16_f32 %0, %1, %2" : "=v"(u1) : "v"(r1.x), "v"(r1.y));    \
    asm("v_cvt_pk_bf16_f32 %0, %1, %2" : "=v"(u2) : "v"(r2.x), "v"(r2.y));    \
    asm("v_cvt_pk_bf16_f32 %0, %1, %2" : "=v"(u3) : "v"(r3.x), "v"(r3.y));    \
    uint4 upk = {u0, u1, u2, u3};                                             \
    *(uint4*)(rslab + (size_t)(TT) * H + hb) = upk;                           \
    v2f q0 = (P00 * r0 + P01 * r1) + (P02 * r2 + P03 * r3);                   \
    v2f q1 = (P10 * r0 + P11 * r1) + (P12 * r2 + P13 * r3);                   \
    float p0 = q0.x + q0.y, p1 = q1.x + q1.y;                                 \
    p0 = dpp_add<0x111, 0xf>(p0); p1 = dpp_add<0x111, 0xf>(p1);               \
    p0 = dpp_add<0x112, 0xf>(p0); p1 = dpp_add<0x112, 0xf>(p1);               \
    p0 = dpp_add<0x114, 0xf>(p0); p1 = dpp_add<0x114, 0xf>(p1);               \
    p0 = dpp_add<0x118, 0xf>(p0); p1 = dpp_add<0x118, 0xf>(p1);               \
    p0 = dpp_add<0x142, 0xa>(p0); p1 = dpp_add<0x142, 0xa>(p1);               \
    p0 = dpp_add<0x143, 0xc>(p0); p1 = dpp_add<0x143, 0xc>(p1);               \
    s0 = bcast63(p0);                                                         \
    s1 = bcast63(p1);                                                         \
    {                                                                         \
        int tc = ((TT) + 4 < T_STEPS) ? (TT) + 4 : T_STEPS - 1;               \
        const float4* vp = (const float4*)(vslab + (size_t)tc * H + hb);      \
        S##a = vp[0]; S##b = vp[1];                                           \
    }                                                                         \
} while (0)

    for (int t = 0; t < T_STEPS; t += 4) {
        PHASE(V0, t);
        PHASE(V1, t + 1);
        PHASE(V2, t + 2);
        PHASE(V3, t + 3);
    }
}

// ---------------------------------------------------------------------------
// Pass C: y[t,b,o] = sum_h Wout[o,h] * r_bf16[b,t,h]; one wave per row.
// ---------------------------------------------------------------------------
__global__ __launch_bounds__(256) void wout_gemv_bf16(
    const unsigned short* __restrict__ rws,  // bf16 overlay in ws
    const float* __restrict__ Wout,          // [3, H]
    float* __restrict__ out)                 // [T, B, 3]
{
    const int row  = blockIdx.x * 4 + (threadIdx.x >> 6);
    const int lane = threadIdx.x & 63;
    const int hb   = 8 * lane;
    const int bq   = row / T_STEPS;
    const int tq   = row - bq * T_STEPS;
    // r short-index: b*T*H*2 + t*H + h
    const size_t ridx = ((size_t)bq * 2 * T_STEPS + tq) * H + hb;

    uint4 u = *(const uint4*)(rws + ridx);
#define UNPK(U) (v2f){__builtin_bit_cast(float, (unsigned)((U) << 16)),       \
                      __builtin_bit_cast(float, (unsigned)((U) & 0xffff0000u))}
    v2f ra0 = UNPK(u.x), ra1 = UNPK(u.y), ra2 = UNPK(u.z), ra3 = UNPK(u.w);

#define GDOT(NAME, O)                                                         \
    float NAME;                                                               \
    {                                                                         \
        const v2f* wp = (const v2f*)(Wout + (O) * H + hb);                    \
        v2f ua = wp[0] * ra0 + wp[1] * ra1;                                   \
        v2f ub = wp[2] * ra2 + wp[3] * ra3;                                   \
        v2f uc = ua + ub;                                                     \
        NAME = uc.x + uc.y;                                                   \
    }
    GDOT(p0, 0) GDOT(p1, 1) GDOT(p2, 2)

#define GRND(CTRL, RM)                                                        \
    p0 = dpp_add<CTRL, RM>(p0); p1 = dpp_add<CTRL, RM>(p1);                   \
    p2 = dpp_add<CTRL, RM>(p2);
    GRND(0x111, 0xf) GRND(0x112, 0xf) GRND(0x114, 0xf)
    GRND(0x118, 0xf) GRND(0x142, 0xa) GRND(0x143, 0xc)

    if (lane == 63) {
        float* o = out + ((size_t)tq * BATCH + bq) * OUTDIM;
        o[0] = p0; o[1] = p1; o[2] = p2;
    }
}

// ---------------------------------------------------------------------------
// Fallback: round-7 fused kernel (used only if ws_size is too small).
// ---------------------------------------------------------------------------
__global__ __launch_bounds__(64, 1) void rnn_scan_fused(
    const float* __restrict__ x, const float* __restrict__ Win,
    const float* __restrict__ Wout, const float* __restrict__ pin,
    const float* __restrict__ pout, const float* __restrict__ l,
    float* __restrict__ out)
{
    const int b    = blockIdx.x;
    const int lane = threadIdx.x;

    __shared__ float4 xs[T_STEPS];
    const float4* x4 = (const float4*)x;
    for (int t = lane; t < T_STEPS; t += 64)
        xs[t] = x4[t * BATCH + b];

    const float l0 = l[0], l1 = l[1];

#define FDECLG(G) v2f fwx##G, fwy##G, fwz##G, fww##G, fA0##G, fA1##G,         \
                      fP0##G, fP1##G, fO0##G, fO1##G, fO2##G, fMM##G;
    FDECLG(0) FDECLG(1) FDECLG(2) FDECLG(3)

#define FLOADG(G, K0) do {                                                    \
    const int h0 = lane + 64 * (K0);                                          \
    const int h1 = h0 + 64;                                                   \
    float4 w0 = ((const float4*)Win)[h0];                                     \
    float4 w1 = ((const float4*)Win)[h1];                                     \
    fwx##G = (v2f){CT * w0.x, CT * w1.x};                                     \
    fwy##G = (v2f){CT * w0.y, CT * w1.y};                                     \
    fwz##G = (v2f){CT * w0.z, CT * w1.z};                                     \
    fww##G = (v2f){CT * w0.w, CT * w1.w};                                     \
    float2 pi0 = ((const float2*)pin)[h0];                                    \
    float2 pi1 = ((const float2*)pin)[h1];                                    \
    fA0##G = (v2f){CT * l0 * pi0.x, CT * l0 * pi1.x};                         \
    fA1##G = (v2f){CT * l1 * pi0.y, CT * l1 * pi1.y};                         \
    float2 q0 = ((const float2*)pout)[h0];                                    \
    float2 q1 = ((const float2*)pout)[h1];                                    \
    fP0##G = (v2f){q0.x, q1.x};                                               \
    fP1##G = (v2f){q0.y, q1.y};                                               \
    fO0##G = (v2f){Wout[0 * H + h0], Wout[0 * H + h1]};                       \
    fO1##G = (v2f){Wout[1 * H + h0], Wout[1 * H + h1]};                       \
    fO2##G = (v2f){Wout[2 * H + h0], Wout[2 * H + h1]};                       \
    fMM##G = (v2f){0.0f, 0.0f};                                               \
} while (0)
    FLOADG(0, 0); FLOADG(1, 2); FLOADG(2, 4); FLOADG(3, 6);

    float s0 = 0.0f, s1 = 0.0f;
    __syncthreads();

    float* outp = out + b * OUTDIM;
    float4 xt = xs[0];
    for (int t = 0; t < T_STEPS; ++t) {
        float4 xn = xs[(t + 1 < T_STEPS) ? t + 1 : 0];
#define FPREW(G) v2f pre##G = fMM##G * LM + fwx##G * xt.x + fwy##G * xt.y     \
                            + fwz##G * xt.z + fww##G * xt.w;
        FPREW(0) FPREW(1) FPREW(2) FPREW(3)
#define FSTEPG(G)                                                             \
        fMM##G = pre##G + fA1##G * s1 + fA0##G * s0;                          \
        v2f r##G;                                                             \
        {                                                                     \
            float e0 = EXP2(fMM##G.x);                                        \
            float e1 = EXP2(fMM##G.y);                                        \
            r##G.x = fmaf(-2.0f, __builtin_amdgcn_rcpf(e0 + 1.0f), 1.0f);     \
            r##G.y = fmaf(-2.0f, __builtin_amdgcn_rcpf(e1 + 1.0f), 1.0f);     \
        }
        FSTEPG(0) FSTEPG(1) FSTEPG(2) FSTEPG(3)
#define FACC(NAME, W)                                                         \
        float NAME;                                                           \
        {                                                                     \
            v2f ua = W##0 * r0 + W##1 * r1;                                   \
            v2f ub = W##2 * r2 + W##3 * r3;                                   \
            v2f uc = ua + ub;                                                 \
            NAME = uc.x + uc.y;                                               \
        }
        FACC(p0, fP0) FACC(p1, fP1) FACC(p2, fO0) FACC(p3, fO1) FACC(p4, fO2)
#define FRND(CTRL, RM)                                                        \
        p0 = dpp_add<CTRL, RM>(p0); p1 = dpp_add<CTRL, RM>(p1);               \
        p2 = dpp_add<CTRL, RM>(p2); p3 = dpp_add<CTRL, RM>(p3);               \
        p4 = dpp_add<CTRL, RM>(p4);
        FRND(0x111, 0xf) FRND(0x112, 0xf) FRND(0x114, 0xf)
        FRND(0x118, 0xf) FRND(0x142, 0xa) FRND(0x143, 0xc)
        s0 = bcast63(p0);
        s1 = bcast63(p1);
        if (lane == 63) {
            float* o = outp + (size_t)t * (BATCH * OUTDIM);
            o[0] = p2; o[1] = p3; o[2] = p4;
        }
        xt = xn;
    }
}

extern "C" void kernel_launch(void* const* d_in, const int* in_sizes, int n_in,
                              void* d_out, int out_size, void* d_ws, size_t ws_size,
                              hipStream_t stream) {
    const float* x    = (const float*)d_in[0];
    const float* Win  = (const float*)d_in[1];
    const float* Wout = (const float*)d_in[2];
    const float* pin  = (const float*)d_in[3];
    const float* pout = (const float*)d_in[4];
    const float* l    = (const float*)d_in[5];
    float* out = (float*)d_out;

    const size_t need = (size_t)T_STEPS * BATCH * H * sizeof(float);  // 131 MB
    if (ws_size >= need) {
        filter_u<<<(BATCH * H) / 256, 256, 0, stream>>>(x, Win, (float*)d_ws);
        rnn_scan_sigma<<<BATCH, 64, 0, stream>>>(pin, pout, l,
                                                 (const float*)d_ws,
                                                 (unsigned short*)d_ws);
        wout_gemv_bf16<<<(T_STEPS * BATCH) / 4, 256, 0, stream>>>(
            (const unsigned short*)d_ws, Wout, out);
    } else {
        rnn_scan_fused<<<BATCH, 64, 0, stream>>>(x, Win, Wout, pin, pout, l, out);
    }
}